// Round 2
// baseline (1182.873 us; speedup 1.0000x reference)
//
#include <hip/hip_runtime.h>
#include <hip/hip_fp16.h>
#include <math.h>

#define N_NODES 500000
#define N_EDGES 4000000
#define FDIM 10   // IN_DIM + HID
#define HID 8

// Dest space: interleaved, dest = 2*col (mi side) or 2*row+1 (mo side).
#define DSPACE (2 * N_NODES)
#define NB 512
#define BSHIFT 11
#define BMASK 2047
#define NB_USED ((DSPACE + BMASK) / 2048)   // 489

#define IN_BLOCKS ((N_NODES + 255) / 256)       // 1954
#define ROWS_PAD (IN_BLOCKS * 256)              // 500224
#define MSTRIDE ((size_t)ROWS_PAD * 10)

// packed fp16 pair
typedef _Float16 h2v __attribute__((ext_vector_type(2)));

__device__ __forceinline__ h2v u2h(unsigned x) {
    union { unsigned u; h2v h; } t; t.u = x; return t.h;
}
__device__ __forceinline__ unsigned packh2(float a, float b) {
    union { __half2 h; unsigned u; } t; t.h = __floats2half2_rn(a, b); return t.u;
}
__device__ __forceinline__ float rfl_f(float x) {
    return __int_as_float(__builtin_amdgcn_readfirstlane(__float_as_int(x)));
}
__device__ __forceinline__ unsigned rfl_u(unsigned x) {
    return (unsigned)__builtin_amdgcn_readfirstlane((int)x);
}

// ---------------------------------------------------------------------------
// Fast transcendentals (hw exp2/rcp; error ~1e-6 vs threshold 1.35e-2)
// ---------------------------------------------------------------------------
__device__ __forceinline__ float fast_tanh(float x) {
    float e = __builtin_amdgcn_exp2f(x * 2.885390082f);  // exp(2x)
    return 1.0f - 2.0f * __builtin_amdgcn_rcpf(e + 1.0f);
}
__device__ __forceinline__ float fast_sigmoid(float x) {
    float e = __builtin_amdgcn_exp2f(-1.442695041f * x); // exp(-x)
    return __builtin_amdgcn_rcpf(1.0f + e);
}

// ---------------------------------------------------------------------------
// Input network: H table (fp16, 16 B rows) + static X table (fp16, 4 B rows).
// ---------------------------------------------------------------------------
__global__ __launch_bounds__(256) void input_kernel(const float* __restrict__ x,
                                                    const float* __restrict__ win_w,
                                                    const float* __restrict__ win_b,
                                                    uint4* __restrict__ xh,
                                                    unsigned* __restrict__ xs) {
    int n = blockIdx.x * 256 + threadIdx.x;   // grid covers ROWS_PAD exactly
    float x0 = 0.f, x1 = 0.f;
    if (n < N_NODES) { x0 = x[2 * n]; x1 = x[2 * n + 1]; }
    float h[HID];
#pragma unroll
    for (int j = 0; j < HID; j++)
        h[j] = fast_tanh(x0 * win_w[j] + x1 * win_w[HID + j] + win_b[j]);
    xh[n] = make_uint4(packh2(h[0], h[1]), packh2(h[2], h[3]),
                       packh2(h[4], h[5]), packh2(h[6], h[7]));
    xs[n] = packh2(x0, x1);
}

// ---------------------------------------------------------------------------
// K0: bucket histogram, LDS-staged.
// ---------------------------------------------------------------------------
__global__ void bucket_hist_kernel(const int* __restrict__ row,
                                   const int* __restrict__ col,
                                   int* __restrict__ g_cnt) {
    __shared__ int s_cnt[NB];
    int tid = threadIdx.x;
    for (int i = tid; i < NB; i += 256) s_cnt[i] = 0;
    __syncthreads();
    int base = blockIdx.x * 4096;
#pragma unroll
    for (int k = 0; k < 16; k++) {
        int e = base + k * 256 + tid;
        if (e < N_EDGES) {
            int c = col[e], r = row[e];
            atomicAdd(&s_cnt[(2 * c) >> BSHIFT], 1);
            atomicAdd(&s_cnt[(2 * r + 1) >> BSHIFT], 1);
        }
    }
    __syncthreads();
    for (int i = tid; i < NB; i += 256) {
        int v = s_cnt[i];
        if (v) atomicAdd(&g_cnt[i], v);
    }
}

// ---------------------------------------------------------------------------
// K1: exclusive scan of bucket counts.
// ---------------------------------------------------------------------------
__global__ void bucket_scan_kernel(const int* __restrict__ g_cnt,
                                   int* __restrict__ bucket_base,
                                   int* __restrict__ bucket_cur) {
    __shared__ int s[NB];
    int t = threadIdx.x;
    int c = g_cnt[t];
    s[t] = c;
    __syncthreads();
    for (int off = 1; off < NB; off <<= 1) {
        int v = (t >= off) ? s[t - off] : 0;
        __syncthreads();
        s[t] += v;
        __syncthreads();
    }
    int ex = s[t] - c;
    bucket_base[t] = ex;
    bucket_cur[t] = ex;
    if (t == NB - 1) bucket_base[NB] = s[t];
}

// ---------------------------------------------------------------------------
// K2: binning into bucket-ordered staging (LDS), coalesced flush.
// ---------------------------------------------------------------------------
__global__ void bin_kernel(const int* __restrict__ row,
                           const int* __restrict__ col,
                           int* __restrict__ bucket_cur,
                           unsigned int* __restrict__ binned) {
    __shared__ int s_cnt[NB];
    __shared__ int s_start[NB];
    __shared__ int s_cur[NB];
    __shared__ int s_gbase[NB];
    __shared__ unsigned int s_items[8192];
    __shared__ unsigned short s_ibkt[8192];

    int tid = threadIdx.x;
    if (tid < NB) s_cnt[tid] = 0;
    __syncthreads();

    int base = blockIdx.x * 4096;
    int cc[4], rr[4];
#pragma unroll
    for (int k = 0; k < 4; k++) {
        int e = base + k * 1024 + tid;
        bool ok = (e < N_EDGES);
        cc[k] = ok ? col[e] : -1;
        rr[k] = ok ? row[e] : -1;
        if (ok) {
            atomicAdd(&s_cnt[(2 * cc[k]) >> BSHIFT], 1);
            atomicAdd(&s_cnt[(2 * rr[k] + 1) >> BSHIFT], 1);
        }
    }
    __syncthreads();

    if (tid < NB) s_start[tid] = s_cnt[tid];
    __syncthreads();
    for (int off = 1; off < NB; off <<= 1) {
        int v = 0;
        if (tid < NB && tid >= off) v = s_start[tid - off];
        __syncthreads();
        if (tid < NB) s_start[tid] += v;
        __syncthreads();
    }
    if (tid < NB) {
        int ex = s_start[tid] - s_cnt[tid];
        s_start[tid] = ex;
        s_cur[tid] = ex;
    }
    __syncthreads();

#pragma unroll
    for (int k = 0; k < 4; k++) {
        if (cc[k] >= 0) {
            int d0 = 2 * cc[k];
            int b0 = d0 >> BSHIFT;
            int s0 = atomicAdd(&s_cur[b0], 1);
            s_items[s0] = ((unsigned)(d0 & BMASK) << 19) | (unsigned)rr[k];
            s_ibkt[s0] = (unsigned short)b0;
            int d1 = 2 * rr[k] + 1;
            int b1 = d1 >> BSHIFT;
            int s1 = atomicAdd(&s_cur[b1], 1);
            s_items[s1] = ((unsigned)(d1 & BMASK) << 19) | (unsigned)cc[k];
            s_ibkt[s1] = (unsigned short)b1;
        }
    }
    __syncthreads();

    if (tid < NB) s_gbase[tid] = atomicAdd(&bucket_cur[tid], s_cnt[tid]);
    __syncthreads();

    int tot = s_start[NB - 1] + s_cnt[NB - 1];
    for (int s = tid; s < tot; s += 1024) {
        int b = s_ibkt[s];
        int g = s_gbase[b] + (s - s_start[b]);
        binned[g] = s_items[s];
    }
}

// ---------------------------------------------------------------------------
// K3: CSR finalize per bucket, all fine-grained work in LDS.
// ---------------------------------------------------------------------------
__global__ void csr_kernel(const unsigned int* __restrict__ binned,
                           const int* __restrict__ bucket_base,
                           int* __restrict__ offs,
                           int* __restrict__ entries) {
    __shared__ int s_deg[2048];
    __shared__ int s_cur[2048];
    __shared__ int s_pair[1024];

    int t = threadIdx.x;
    int b = blockIdx.x;
    if (b == 0 && t == 0) offs[DSPACE] = 2 * N_EDGES;

    int ebase = bucket_base[b];
    int eend = bucket_base[b + 1];

    s_deg[t] = 0;
    s_deg[t + 1024] = 0;
    __syncthreads();

    for (int p = ebase + t; p < eend; p += 1024)
        atomicAdd(&s_deg[binned[p] >> 19], 1);
    __syncthreads();

    int d0 = s_deg[2 * t], d1 = s_deg[2 * t + 1];
    s_pair[t] = d0 + d1;
    __syncthreads();
    for (int off = 1; off < 1024; off <<= 1) {
        int v = (t >= off) ? s_pair[t - off] : 0;
        __syncthreads();
        s_pair[t] += v;
        __syncthreads();
    }
    int pex = s_pair[t] - (d0 + d1);
    s_cur[2 * t] = pex;
    s_cur[2 * t + 1] = pex + d0;

    int dest0 = b * 2048 + 2 * t;
    if (dest0 < DSPACE) offs[dest0] = ebase + pex;
    if (dest0 + 1 < DSPACE) offs[dest0 + 1] = ebase + pex + d0;
    __syncthreads();

    for (int p = ebase + t; p < eend; p += 1024) {
        unsigned int it = binned[p];
        int dl = it >> 19;
        int other = it & 0x7FFFF;
        int pos = atomicAdd(&s_cur[dl], 1);
        entries[ebase + pos] = other;
    }
}

// ---------------------------------------------------------------------------
// Node gather loop: one thread per dest, side is BLOCK-uniform
// (blocks [0,IN_BLOCKS) = even dests / mi, [IN_BLOCKS,2*IN_BLOCKS) = odd / mo).
// Other-half e1 weights packed half2 in SGPRs (readfirstlane), dot via
// v_dot2_f32_f16 (f32 accumulate -> same numerics as before).
// Writes per-dest message m[10] (f32) to global; node net is a separate pass.
// ---------------------------------------------------------------------------
__global__ __launch_bounds__(256, 6) void node_loop_kernel(
        const uint4* __restrict__ xh,
        const unsigned* __restrict__ xs,
        const int* __restrict__ offs,
        const int* __restrict__ entries,
        const float* __restrict__ e1_w,
        const float* __restrict__ e1_b,
        const float* __restrict__ e2_w,
        const float* __restrict__ e2_b,
        float* __restrict__ m_out) {     // [2][ROWS_PAD*10]
    __shared__ uint4 s_self4[10];        // self-half weights, packed half2, kk-major
    __shared__ unsigned s_oth[40];       // other-half weights, packed half2
    __shared__ float s_scal[17];         // e1b[8], e2w[8], e2b

    int tid = threadIdx.x;
    int side = (blockIdx.x >= IN_BLOCKS) ? 1 : 0;   // 0: mi (dest even), 1: mo
    int selfBase = side ? 10 : 0;   // mi: self=col half (rows 0..9)
    int othBase  = side ? 0 : 10;

    unsigned* s_self = (unsigned*)s_self4;
    if (tid < 40) {
        int kk = tid >> 3, j = tid & 7;
        s_self[tid] = packh2(e1_w[(selfBase + 2 * kk) * HID + j],
                             e1_w[(selfBase + 2 * kk + 1) * HID + j]);
        s_oth[tid]  = packh2(e1_w[(othBase + 2 * kk) * HID + j],
                             e1_w[(othBase + 2 * kk + 1) * HID + j]);
    } else if (tid < 48) s_scal[tid - 40] = e1_b[tid - 48 + 8];
    else if (tid < 56) s_scal[tid - 40] = e2_w[tid - 48];
    else if (tid == 56) s_scal[16] = e2_b[0];
    __syncthreads();

    // hoist wave-uniform constants to SGPRs
    unsigned so[40];
#pragma unroll
    for (int i = 0; i < 40; i++) so[i] = rfl_u(s_oth[i]);
    float sb[HID], sv[HID];
#pragma unroll
    for (int j = 0; j < HID; j++) { sb[j] = rfl_f(s_scal[j]); sv[j] = rfl_f(s_scal[8 + j]); }
    float sc = rfl_f(s_scal[16]);

    int n = (blockIdx.x - side * IN_BLOCKS) * 256 + tid;
    if (n >= N_NODES) return;
    int dest = 2 * n + side;

    // self-half dot (bias folded), inputs stay fp16-packed
    uint4 xq = xh[n]; unsigned xx = xs[n];
    unsigned xp[5] = { xq.x, xq.y, xq.z, xq.w, xx };
    float us[HID];
#pragma unroll
    for (int j = 0; j < HID; j++) us[j] = sb[j];
#pragma unroll
    for (int kk = 0; kk < 5; kk++) {
        uint4 wa = s_self4[2 * kk];
        uint4 wb = s_self4[2 * kk + 1];
        h2v a = u2h(xp[kk]);
        us[0] = __builtin_amdgcn_fdot2(a, u2h(wa.x), us[0], false);
        us[1] = __builtin_amdgcn_fdot2(a, u2h(wa.y), us[1], false);
        us[2] = __builtin_amdgcn_fdot2(a, u2h(wa.z), us[2], false);
        us[3] = __builtin_amdgcn_fdot2(a, u2h(wa.w), us[3], false);
        us[4] = __builtin_amdgcn_fdot2(a, u2h(wb.x), us[4], false);
        us[5] = __builtin_amdgcn_fdot2(a, u2h(wb.y), us[5], false);
        us[6] = __builtin_amdgcn_fdot2(a, u2h(wb.z), us[6], false);
        us[7] = __builtin_amdgcn_fdot2(a, u2h(wb.w), us[7], false);
    }

    int p0 = offs[dest], p1 = offs[dest + 1];
    float m[FDIM];
#pragma unroll
    for (int k = 0; k < FDIM; k++) m[k] = 0.f;

    uint4 cH = make_uint4(0, 0, 0, 0); unsigned cX = 0;
    if (p0 < p1) { int o = entries[p0]; cH = xh[o]; cX = xs[o]; }
    for (int p = p0; p < p1; ++p) {
        uint4 nH = cH; unsigned nX = cX;
        if (p + 1 < p1) { int o2 = entries[p + 1]; nH = xh[o2]; nX = xs[o2]; }

        unsigned cp[5] = { cH.x, cH.y, cH.z, cH.w, cX };
        float acc[HID];
#pragma unroll
        for (int j = 0; j < HID; j++) acc[j] = us[j];
#pragma unroll
        for (int kk = 0; kk < 5; kk++) {
            h2v a = u2h(cp[kk]);
#pragma unroll
            for (int j = 0; j < HID; j++)
                acc[j] = __builtin_amdgcn_fdot2(a, u2h(so[kk * 8 + j]), acc[j], false);
        }
        float d = sc;
#pragma unroll
        for (int j = 0; j < HID; j++) d += fast_tanh(acc[j]) * sv[j];
        float e = fast_sigmoid(d);
#pragma unroll
        for (int kk = 0; kk < 5; kk++) {
            h2v a = u2h(cp[kk]);
            m[2 * kk]     += e * (float)a.x;
            m[2 * kk + 1] += e * (float)a.y;
        }
        cH = nH; cX = nX;
    }

    float2* md = (float2*)(m_out + (size_t)side * MSTRIDE + (size_t)n * 10);
    md[0] = make_float2(m[0], m[1]);
    md[1] = make_float2(m[2], m[3]);
    md[2] = make_float2(m[4], m[5]);
    md[3] = make_float2(m[6], m[7]);
    md[4] = make_float2(m[8], m[9]);
}

// ---------------------------------------------------------------------------
// Node network: pure streaming pass (reads m, xh, xs; writes xh_next).
// ---------------------------------------------------------------------------
__global__ __launch_bounds__(256) void node_net_kernel(
        const uint4* __restrict__ xh,
        const unsigned* __restrict__ xs,
        const float* __restrict__ m_in,
        const float* __restrict__ n1_w,
        const float* __restrict__ n1_b,
        const float* __restrict__ n2_w,
        const float* __restrict__ n2_b,
        uint4* __restrict__ xh_next) {
    __shared__ float s_n1w[30 * HID];
    __shared__ float s_n1b[HID];
    __shared__ float s_n2w[HID * HID];
    __shared__ float s_n2b[HID];
    int tid = threadIdx.x;
    if (tid < 240) s_n1w[tid] = n1_w[tid];
    else if (tid < 248) s_n1b[tid - 240] = n1_b[tid - 240];
    if (tid < 64) s_n2w[tid] = n2_w[tid];
    else if (tid < 72) s_n2b[tid - 64] = n2_b[tid - 64];
    __syncthreads();

    int n = blockIdx.x * 256 + tid;
    if (n >= N_NODES) return;

    float mi[FDIM], mo[FDIM];
    const float2* p_mi = (const float2*)(m_in + (size_t)n * 10);
    const float2* p_mo = (const float2*)(m_in + MSTRIDE + (size_t)n * 10);
#pragma unroll
    for (int k = 0; k < 5; k++) {
        float2 a = p_mi[k]; mi[2 * k] = a.x; mi[2 * k + 1] = a.y;
        float2 b = p_mo[k]; mo[2 * k] = b.x; mo[2 * k + 1] = b.y;
    }
    uint4 xq = xh[n]; unsigned xx = xs[n];
    unsigned xp[5] = { xq.x, xq.y, xq.z, xq.w, xx };
    float xn[FDIM];
#pragma unroll
    for (int kk = 0; kk < 5; kk++) {
        h2v a = u2h(xp[kk]);
        xn[2 * kk] = (float)a.x; xn[2 * kk + 1] = (float)a.y;
    }

    float h1[HID];
#pragma unroll
    for (int j = 0; j < HID; j++) h1[j] = s_n1b[j];
#pragma unroll
    for (int k = 0; k < FDIM; k++) {
#pragma unroll
        for (int j = 0; j < HID; j++) {
            h1[j] += mi[k] * s_n1w[k * HID + j];
            h1[j] += mo[k] * s_n1w[(FDIM + k) * HID + j];
            h1[j] += xn[k] * s_n1w[(2 * FDIM + k) * HID + j];
        }
    }
#pragma unroll
    for (int j = 0; j < HID; j++) h1[j] = fast_tanh(h1[j]);

    float H[HID];
#pragma unroll
    for (int j = 0; j < HID; j++) H[j] = s_n2b[j];
#pragma unroll
    for (int k = 0; k < HID; k++) {
#pragma unroll
        for (int j = 0; j < HID; j++) H[j] += h1[k] * s_n2w[k * HID + j];
    }
#pragma unroll
    for (int j = 0; j < HID; j++) H[j] = fast_tanh(H[j]);

    xh_next[n] = make_uint4(packh2(H[0], H[1]), packh2(H[2], H[3]),
                            packh2(H[4], H[5]), packh2(H[6], H[7]));
}

// ---------------------------------------------------------------------------
// Final edge network -> out. Top-half weights in SGPRs, bottom half via LDS
// b128 reads; dots via v_dot2_f32_f16.
// ---------------------------------------------------------------------------
__global__ __launch_bounds__(256) void edge_kernel(const int* __restrict__ row,
                                                   const int* __restrict__ col,
                                                   const uint4* __restrict__ xh,
                                                   const unsigned* __restrict__ xs,
                                                   const float* __restrict__ e1_w,
                                                   const float* __restrict__ e1_b,
                                                   const float* __restrict__ e2_w,
                                                   const float* __restrict__ e2_b,
                                                   float* __restrict__ out) {
    __shared__ unsigned s_top[40];
    __shared__ uint4 s_bot4[10];
    __shared__ float s_scal[17];
    int tid = threadIdx.x;
    unsigned* s_bot = (unsigned*)s_bot4;
    if (tid < 40) {
        int kk = tid >> 3, j = tid & 7;
        s_top[tid] = packh2(e1_w[(2 * kk) * HID + j], e1_w[(2 * kk + 1) * HID + j]);
        s_bot[tid] = packh2(e1_w[(FDIM + 2 * kk) * HID + j], e1_w[(FDIM + 2 * kk + 1) * HID + j]);
    } else if (tid < 48) s_scal[tid - 40] = e1_b[tid - 48 + 8];
    else if (tid < 56) s_scal[tid - 40] = e2_w[tid - 48];
    else if (tid == 56) s_scal[16] = e2_b[0];
    __syncthreads();

    unsigned st[40];
#pragma unroll
    for (int i = 0; i < 40; i++) st[i] = rfl_u(s_top[i]);
    float sb[HID], sv[HID];
#pragma unroll
    for (int j = 0; j < HID; j++) { sb[j] = rfl_f(s_scal[j]); sv[j] = rfl_f(s_scal[8 + j]); }
    float sc = rfl_f(s_scal[16]);

    int i = blockIdx.x * 256 + tid;
    if (i >= N_EDGES) return;

    int r = row[i], c = col[i];
    uint4 aq = xh[c]; unsigned ax = xs[c];
    uint4 bq = xh[r]; unsigned bx = xs[r];
    unsigned ap[5] = { aq.x, aq.y, aq.z, aq.w, ax };
    unsigned bp[5] = { bq.x, bq.y, bq.z, bq.w, bx };

    float acc[HID];
#pragma unroll
    for (int j = 0; j < HID; j++) acc[j] = sb[j];
#pragma unroll
    for (int kk = 0; kk < 5; kk++) {
        h2v a = u2h(ap[kk]);
#pragma unroll
        for (int j = 0; j < HID; j++)
            acc[j] = __builtin_amdgcn_fdot2(a, u2h(st[kk * 8 + j]), acc[j], false);
    }
#pragma unroll
    for (int kk = 0; kk < 5; kk++) {
        uint4 wa = s_bot4[2 * kk];
        uint4 wb = s_bot4[2 * kk + 1];
        h2v b = u2h(bp[kk]);
        acc[0] = __builtin_amdgcn_fdot2(b, u2h(wa.x), acc[0], false);
        acc[1] = __builtin_amdgcn_fdot2(b, u2h(wa.y), acc[1], false);
        acc[2] = __builtin_amdgcn_fdot2(b, u2h(wa.z), acc[2], false);
        acc[3] = __builtin_amdgcn_fdot2(b, u2h(wa.w), acc[3], false);
        acc[4] = __builtin_amdgcn_fdot2(b, u2h(wb.x), acc[4], false);
        acc[5] = __builtin_amdgcn_fdot2(b, u2h(wb.y), acc[5], false);
        acc[6] = __builtin_amdgcn_fdot2(b, u2h(wb.z), acc[6], false);
        acc[7] = __builtin_amdgcn_fdot2(b, u2h(wb.w), acc[7], false);
    }

    float d = sc;
#pragma unroll
    for (int j = 0; j < HID; j++) d += fast_tanh(acc[j]) * sv[j];
    out[i] = fast_sigmoid(d);
}

// ---------------------------------------------------------------------------
extern "C" void kernel_launch(void* const* d_in, const int* in_sizes, int n_in,
                              void* d_out, int out_size, void* d_ws, size_t ws_size,
                              hipStream_t stream) {
    const float* x      = (const float*)d_in[0];
    const int*   eidx   = (const int*)d_in[1];
    const float* win_w  = (const float*)d_in[2];
    const float* win_b  = (const float*)d_in[3];
    const float* e1_w   = (const float*)d_in[4];
    const float* e1_b   = (const float*)d_in[5];
    const float* e2_w   = (const float*)d_in[6];
    const float* e2_b   = (const float*)d_in[7];
    const float* n1_w   = (const float*)d_in[8];
    const float* n1_b   = (const float*)d_in[9];
    const float* n2_w   = (const float*)d_in[10];
    const float* n2_b   = (const float*)d_in[11];
    float* out = (float*)d_out;

    const int* row = eidx;
    const int* col = eidx + N_EDGES;

    // Workspace layout (~94 MB). m (40 MB, iteration phase) overlaps
    // binned (32 MB, build phase only) — they are never live together.
    char* w = (char*)d_ws;
    uint4* xh0 = (uint4*)w;            w += (size_t)ROWS_PAD * 16;   // 8 MB
    uint4* xh1 = (uint4*)w;            w += (size_t)ROWS_PAD * 16;   // 8 MB
    unsigned* xs = (unsigned*)w;       w += (size_t)ROWS_PAD * 4;    // 2 MB
    int* entries = (int*)w;            w += (size_t)2 * N_EDGES * 4; // 32 MB
    int* offs = (int*)w;               w += (size_t)(DSPACE + 64) * 4;
    int* g_cnt = (int*)w;              w += NB * 4;
    int* bucket_base = (int*)w;        w += (NB + 64) * 4;
    int* bucket_cur = (int*)w;         w += NB * 4;
    w = (char*)(((uintptr_t)w + 255) & ~(uintptr_t)255);
    float* m = (float*)w;                        // 2*MSTRIDE floats = 40 MB
    unsigned int* binned = (unsigned int*)w;     // 2E uints = 32 MB (build only)

    const int BLK = 256;
    int edge_blocks = (N_EDGES + BLK - 1) / BLK;
    int chunk_blocks = (N_EDGES + 4095) / 4096;

    // --- CSR build ---
    hipMemsetAsync(g_cnt, 0, NB * sizeof(int), stream);
    bucket_hist_kernel<<<chunk_blocks, 256, 0, stream>>>(row, col, g_cnt);
    bucket_scan_kernel<<<1, NB, 0, stream>>>(g_cnt, bucket_base, bucket_cur);
    bin_kernel<<<chunk_blocks, 1024, 0, stream>>>(row, col, bucket_cur, binned);
    csr_kernel<<<NB_USED, 1024, 0, stream>>>(binned, bucket_base, offs, entries);

    // --- input network ---
    input_kernel<<<IN_BLOCKS, BLK, 0, stream>>>(x, win_w, win_b, xh0, xs);

    // --- message-passing iterations ---
    uint4* cur = xh0;
    uint4* nxt = xh1;
    for (int it = 0; it < 3; it++) {
        node_loop_kernel<<<2 * IN_BLOCKS, BLK, 0, stream>>>(
            cur, xs, offs, entries, e1_w, e1_b, e2_w, e2_b, m);
        node_net_kernel<<<IN_BLOCKS, BLK, 0, stream>>>(
            cur, xs, m, n1_w, n1_b, n2_w, n2_b, nxt);
        uint4* t = cur; cur = nxt; nxt = t;
    }

    // --- final edge network -> out ---
    edge_kernel<<<edge_blocks, BLK, 0, stream>>>(
        row, col, cur, xs, e1_w, e1_b, e2_w, e2_b, out);
}

// Round 3
// 986.547 us; speedup vs baseline: 1.1990x; 1.1990x over previous
//
#include <hip/hip_runtime.h>
#include <hip/hip_fp16.h>
#include <math.h>

#define N_NODES 500000
#define N_EDGES 4000000
#define FDIM 10   // IN_DIM + HID
#define HID 8

// Dest space: interleaved, dest = 2*col (mi side) or 2*row+1 (mo side).
#define DSPACE (2 * N_NODES)
#define NB 512
#define BSHIFT 11
#define BMASK 2047
#define NB_USED ((DSPACE + BMASK) / 2048)   // 489

#define IN_BLOCKS ((N_NODES + 255) / 256)       // 1954
#define ROWS_PAD (IN_BLOCKS * 256)              // 500224
#define NODE_BLOCKS2 ((N_NODES + 127) / 128)    // 3907 (128 nodes/block, 2 sides)

// packed fp16 pair
typedef _Float16 h2v __attribute__((ext_vector_type(2)));

__device__ __forceinline__ h2v u2h(unsigned x) {
    union { unsigned u; h2v h; } t; t.u = x; return t.h;
}
__device__ __forceinline__ unsigned packh2(float a, float b) {
    union { __half2 h; unsigned u; } t; t.h = __floats2half2_rn(a, b); return t.u;
}
__device__ __forceinline__ float rfl_f(float x) {
    return __int_as_float(__builtin_amdgcn_readfirstlane(__float_as_int(x)));
}
__device__ __forceinline__ unsigned rfl_u(unsigned x) {
    return (unsigned)__builtin_amdgcn_readfirstlane((int)x);
}

// ---------------------------------------------------------------------------
// Fast transcendentals (hw exp2/rcp; error ~1e-6 vs threshold 1.35e-2)
// ---------------------------------------------------------------------------
__device__ __forceinline__ float fast_tanh(float x) {
    float e = __builtin_amdgcn_exp2f(x * 2.885390082f);  // exp(2x)
    return 1.0f - 2.0f * __builtin_amdgcn_rcpf(e + 1.0f);
}
__device__ __forceinline__ float fast_sigmoid(float x) {
    float e = __builtin_amdgcn_exp2f(-1.442695041f * x); // exp(-x)
    return __builtin_amdgcn_rcpf(1.0f + e);
}

// ---------------------------------------------------------------------------
// Input network: H table (fp16, 16 B rows) + static X table (fp16, 4 B rows).
// ---------------------------------------------------------------------------
__global__ __launch_bounds__(256) void input_kernel(const float* __restrict__ x,
                                                    const float* __restrict__ win_w,
                                                    const float* __restrict__ win_b,
                                                    uint4* __restrict__ xh,
                                                    unsigned* __restrict__ xs) {
    int n = blockIdx.x * 256 + threadIdx.x;   // grid covers ROWS_PAD exactly
    float x0 = 0.f, x1 = 0.f;
    if (n < N_NODES) { x0 = x[2 * n]; x1 = x[2 * n + 1]; }
    float h[HID];
#pragma unroll
    for (int j = 0; j < HID; j++)
        h[j] = fast_tanh(x0 * win_w[j] + x1 * win_w[HID + j] + win_b[j]);
    xh[n] = make_uint4(packh2(h[0], h[1]), packh2(h[2], h[3]),
                       packh2(h[4], h[5]), packh2(h[6], h[7]));
    xs[n] = packh2(x0, x1);
}

// ---------------------------------------------------------------------------
// K0: bucket histogram, LDS-staged.
// ---------------------------------------------------------------------------
__global__ void bucket_hist_kernel(const int* __restrict__ row,
                                   const int* __restrict__ col,
                                   int* __restrict__ g_cnt) {
    __shared__ int s_cnt[NB];
    int tid = threadIdx.x;
    for (int i = tid; i < NB; i += 256) s_cnt[i] = 0;
    __syncthreads();
    int base = blockIdx.x * 4096;
#pragma unroll
    for (int k = 0; k < 16; k++) {
        int e = base + k * 256 + tid;
        if (e < N_EDGES) {
            int c = col[e], r = row[e];
            atomicAdd(&s_cnt[(2 * c) >> BSHIFT], 1);
            atomicAdd(&s_cnt[(2 * r + 1) >> BSHIFT], 1);
        }
    }
    __syncthreads();
    for (int i = tid; i < NB; i += 256) {
        int v = s_cnt[i];
        if (v) atomicAdd(&g_cnt[i], v);
    }
}

// ---------------------------------------------------------------------------
// K1: exclusive scan of bucket counts.
// ---------------------------------------------------------------------------
__global__ void bucket_scan_kernel(const int* __restrict__ g_cnt,
                                   int* __restrict__ bucket_base,
                                   int* __restrict__ bucket_cur) {
    __shared__ int s[NB];
    int t = threadIdx.x;
    int c = g_cnt[t];
    s[t] = c;
    __syncthreads();
    for (int off = 1; off < NB; off <<= 1) {
        int v = (t >= off) ? s[t - off] : 0;
        __syncthreads();
        s[t] += v;
        __syncthreads();
    }
    int ex = s[t] - c;
    bucket_base[t] = ex;
    bucket_cur[t] = ex;
    if (t == NB - 1) bucket_base[NB] = s[t];
}

// ---------------------------------------------------------------------------
// K2: binning into bucket-ordered staging (LDS), coalesced flush.
// ---------------------------------------------------------------------------
__global__ void bin_kernel(const int* __restrict__ row,
                           const int* __restrict__ col,
                           int* __restrict__ bucket_cur,
                           unsigned int* __restrict__ binned) {
    __shared__ int s_cnt[NB];
    __shared__ int s_start[NB];
    __shared__ int s_cur[NB];
    __shared__ int s_gbase[NB];
    __shared__ unsigned int s_items[8192];
    __shared__ unsigned short s_ibkt[8192];

    int tid = threadIdx.x;
    if (tid < NB) s_cnt[tid] = 0;
    __syncthreads();

    int base = blockIdx.x * 4096;
    int cc[4], rr[4];
#pragma unroll
    for (int k = 0; k < 4; k++) {
        int e = base + k * 1024 + tid;
        bool ok = (e < N_EDGES);
        cc[k] = ok ? col[e] : -1;
        rr[k] = ok ? row[e] : -1;
        if (ok) {
            atomicAdd(&s_cnt[(2 * cc[k]) >> BSHIFT], 1);
            atomicAdd(&s_cnt[(2 * rr[k] + 1) >> BSHIFT], 1);
        }
    }
    __syncthreads();

    if (tid < NB) s_start[tid] = s_cnt[tid];
    __syncthreads();
    for (int off = 1; off < NB; off <<= 1) {
        int v = 0;
        if (tid < NB && tid >= off) v = s_start[tid - off];
        __syncthreads();
        if (tid < NB) s_start[tid] += v;
        __syncthreads();
    }
    if (tid < NB) {
        int ex = s_start[tid] - s_cnt[tid];
        s_start[tid] = ex;
        s_cur[tid] = ex;
    }
    __syncthreads();

#pragma unroll
    for (int k = 0; k < 4; k++) {
        if (cc[k] >= 0) {
            int d0 = 2 * cc[k];
            int b0 = d0 >> BSHIFT;
            int s0 = atomicAdd(&s_cur[b0], 1);
            s_items[s0] = ((unsigned)(d0 & BMASK) << 19) | (unsigned)rr[k];
            s_ibkt[s0] = (unsigned short)b0;
            int d1 = 2 * rr[k] + 1;
            int b1 = d1 >> BSHIFT;
            int s1 = atomicAdd(&s_cur[b1], 1);
            s_items[s1] = ((unsigned)(d1 & BMASK) << 19) | (unsigned)cc[k];
            s_ibkt[s1] = (unsigned short)b1;
        }
    }
    __syncthreads();

    if (tid < NB) s_gbase[tid] = atomicAdd(&bucket_cur[tid], s_cnt[tid]);
    __syncthreads();

    int tot = s_start[NB - 1] + s_cnt[NB - 1];
    for (int s = tid; s < tot; s += 1024) {
        int b = s_ibkt[s];
        int g = s_gbase[b] + (s - s_start[b]);
        binned[g] = s_items[s];
    }
}

// ---------------------------------------------------------------------------
// K3: CSR finalize per bucket, all fine-grained work in LDS.
// ---------------------------------------------------------------------------
__global__ void csr_kernel(const unsigned int* __restrict__ binned,
                           const int* __restrict__ bucket_base,
                           int* __restrict__ offs,
                           int* __restrict__ entries) {
    __shared__ int s_deg[2048];
    __shared__ int s_cur[2048];
    __shared__ int s_pair[1024];

    int t = threadIdx.x;
    int b = blockIdx.x;
    if (b == 0 && t == 0) offs[DSPACE] = 2 * N_EDGES;

    int ebase = bucket_base[b];
    int eend = bucket_base[b + 1];

    s_deg[t] = 0;
    s_deg[t + 1024] = 0;
    __syncthreads();

    for (int p = ebase + t; p < eend; p += 1024)
        atomicAdd(&s_deg[binned[p] >> 19], 1);
    __syncthreads();

    int d0 = s_deg[2 * t], d1 = s_deg[2 * t + 1];
    s_pair[t] = d0 + d1;
    __syncthreads();
    for (int off = 1; off < 1024; off <<= 1) {
        int v = (t >= off) ? s_pair[t - off] : 0;
        __syncthreads();
        s_pair[t] += v;
        __syncthreads();
    }
    int pex = s_pair[t] - (d0 + d1);
    s_cur[2 * t] = pex;
    s_cur[2 * t + 1] = pex + d0;

    int dest0 = b * 2048 + 2 * t;
    if (dest0 < DSPACE) offs[dest0] = ebase + pex;
    if (dest0 + 1 < DSPACE) offs[dest0 + 1] = ebase + pex + d0;
    __syncthreads();

    for (int p = ebase + t; p < eend; p += 1024) {
        unsigned int it = binned[p];
        int dl = it >> 19;
        int other = it & 0x7FFFF;
        int pos = atomicAdd(&s_cur[dl], 1);
        entries[ebase + pos] = other;
    }
}

// ---------------------------------------------------------------------------
// Fused gather + edge-MLP + node network.
//   256 threads / 128 nodes per block: tid<128 -> dest 2n (mi side),
//   tid>=128 -> dest 2n+1 (mo side). Side is WAVE-uniform (128 = 2 waves),
//   so the other-half e1 weights are hoisted to SGPRs per wave.
//   Inner dot via v_dot2_f32_f16 on fp16-packed gathered rows (f32 accum).
//   mo messages cross to the mi threads via LDS for the fused node net.
// ---------------------------------------------------------------------------
__global__ __launch_bounds__(256, 6) void node_kernel(
        const uint4* __restrict__ xh,
        const unsigned* __restrict__ xs,
        const int* __restrict__ offs,
        const int* __restrict__ entries,
        const float* __restrict__ e1_w,
        const float* __restrict__ e1_b,
        const float* __restrict__ e2_w,
        const float* __restrict__ e2_b,
        const float* __restrict__ n1_w,
        const float* __restrict__ n1_b,
        const float* __restrict__ n2_w,
        const float* __restrict__ n2_b,
        uint4* __restrict__ xh_next) {
    __shared__ uint4 s_wtop4[10];     // e1_w rows 0..9  (col half), packed half2
    __shared__ uint4 s_wbot4[10];     // e1_w rows 10..19 (row half), packed half2
    __shared__ float s_scal[17];      // e1b[8], e2w[8], e2b
    __shared__ float s_n1w[30 * HID];
    __shared__ float s_n1b[HID];
    __shared__ float s_n2w[HID * HID];
    __shared__ float s_n2b[HID];
    __shared__ float s_mo[128 * 11];  // stride 11 (coprime 32 -> no conflicts)

    int tid = threadIdx.x;
    if (tid < 40) {
        int kk = tid >> 3, j = tid & 7;
        ((unsigned*)s_wtop4)[tid] = packh2(e1_w[(2 * kk) * HID + j],
                                           e1_w[(2 * kk + 1) * HID + j]);
        ((unsigned*)s_wbot4)[tid] = packh2(e1_w[(FDIM + 2 * kk) * HID + j],
                                           e1_w[(FDIM + 2 * kk + 1) * HID + j]);
    } else if (tid < 48) s_scal[tid - 40] = e1_b[tid - 40];
    else if (tid < 56) s_scal[tid - 40] = e2_w[tid - 48];
    else if (tid == 56) s_scal[16] = e2_b[0];
    if (tid < 240) s_n1w[tid] = n1_w[tid];
    else if (tid < 248) s_n1b[tid - 240] = n1_b[tid - 240];
    if (tid < 64) s_n2w[tid] = n2_w[tid];
    else if (tid < 72) s_n2b[tid - 64] = n2_b[tid - 64];
    __syncthreads();

    bool up = tid >= 128;             // wave-uniform
    int lt = up ? tid - 128 : tid;
    int n = blockIdx.x * 128 + lt;
    bool act = n < N_NODES;

    // mi (dest 2n): self = top half, other = bottom half. mo: swapped.
    const uint4* selfw4 = up ? s_wbot4 : s_wtop4;
    const unsigned* othw = up ? (const unsigned*)s_wtop4 : (const unsigned*)s_wbot4;

    // wave-uniform constants -> SGPRs
    unsigned so[40];
#pragma unroll
    for (int i = 0; i < 40; i++) so[i] = rfl_u(othw[i]);
    float sb[HID], sv[HID];
#pragma unroll
    for (int j = 0; j < HID; j++) { sb[j] = rfl_f(s_scal[j]); sv[j] = rfl_f(s_scal[8 + j]); }
    float sc = rfl_f(s_scal[16]);

    unsigned xp[5] = {0, 0, 0, 0, 0};
    float m[FDIM];
#pragma unroll
    for (int k = 0; k < FDIM; k++) m[k] = 0.f;

    if (act) {
        uint4 xq = xh[n]; unsigned xx = xs[n];
        xp[0] = xq.x; xp[1] = xq.y; xp[2] = xq.z; xp[3] = xq.w; xp[4] = xx;

        // self-half dot (bias folded), inputs stay fp16-packed
        float us[HID];
#pragma unroll
        for (int j = 0; j < HID; j++) us[j] = sb[j];
#pragma unroll
        for (int kk = 0; kk < 5; kk++) {
            uint4 wa = selfw4[2 * kk];
            uint4 wb = selfw4[2 * kk + 1];
            h2v a = u2h(xp[kk]);
            us[0] = __builtin_amdgcn_fdot2(a, u2h(wa.x), us[0], false);
            us[1] = __builtin_amdgcn_fdot2(a, u2h(wa.y), us[1], false);
            us[2] = __builtin_amdgcn_fdot2(a, u2h(wa.z), us[2], false);
            us[3] = __builtin_amdgcn_fdot2(a, u2h(wa.w), us[3], false);
            us[4] = __builtin_amdgcn_fdot2(a, u2h(wb.x), us[4], false);
            us[5] = __builtin_amdgcn_fdot2(a, u2h(wb.y), us[5], false);
            us[6] = __builtin_amdgcn_fdot2(a, u2h(wb.z), us[6], false);
            us[7] = __builtin_amdgcn_fdot2(a, u2h(wb.w), us[7], false);
        }

        int dest = 2 * n + (up ? 1 : 0);
        int p0 = offs[dest], p1 = offs[dest + 1];

        uint4 cH = make_uint4(0, 0, 0, 0); unsigned cX = 0;
        if (p0 < p1) { int o = entries[p0]; cH = xh[o]; cX = xs[o]; }
        for (int p = p0; p < p1; ++p) {
            // prefetch next neighbor row before consuming current
            uint4 nH = cH; unsigned nX = cX;
            if (p + 1 < p1) { int o2 = entries[p + 1]; nH = xh[o2]; nX = xs[o2]; }

            unsigned cp[5] = { cH.x, cH.y, cH.z, cH.w, cX };
            float acc[HID];
#pragma unroll
            for (int j = 0; j < HID; j++) acc[j] = us[j];
#pragma unroll
            for (int kk = 0; kk < 5; kk++) {
                h2v a = u2h(cp[kk]);
#pragma unroll
                for (int j = 0; j < HID; j++)
                    acc[j] = __builtin_amdgcn_fdot2(a, u2h(so[kk * 8 + j]), acc[j], false);
            }
            float d = sc;
#pragma unroll
            for (int j = 0; j < HID; j++) d += fast_tanh(acc[j]) * sv[j];
            float e = fast_sigmoid(d);
#pragma unroll
            for (int kk = 0; kk < 5; kk++) {
                h2v a = u2h(cp[kk]);
                m[2 * kk]     += e * (float)a.x;
                m[2 * kk + 1] += e * (float)a.y;
            }
            cH = nH; cX = nX;
        }
    }

    if (up && act) {
        int lb = lt * 11;
#pragma unroll
        for (int k = 0; k < FDIM; k++) s_mo[lb + k] = m[k];
    }
    __syncthreads();

    if (!up && act) {
        int lb = lt * 11;
        float xn[FDIM];
#pragma unroll
        for (int kk = 0; kk < 5; kk++) {
            h2v a = u2h(xp[kk]);
            xn[2 * kk] = (float)a.x; xn[2 * kk + 1] = (float)a.y;
        }
        float h1[HID];
#pragma unroll
        for (int j = 0; j < HID; j++) h1[j] = s_n1b[j];
#pragma unroll
        for (int k = 0; k < FDIM; k++) {
            float mo_k = s_mo[lb + k];
#pragma unroll
            for (int j = 0; j < HID; j++) {
                h1[j] += m[k]  * s_n1w[k * HID + j];
                h1[j] += mo_k  * s_n1w[(FDIM + k) * HID + j];
                h1[j] += xn[k] * s_n1w[(2 * FDIM + k) * HID + j];
            }
        }
#pragma unroll
        for (int j = 0; j < HID; j++) h1[j] = fast_tanh(h1[j]);

        float H[HID];
#pragma unroll
        for (int j = 0; j < HID; j++) H[j] = s_n2b[j];
#pragma unroll
        for (int k = 0; k < HID; k++) {
#pragma unroll
            for (int j = 0; j < HID; j++) H[j] += h1[k] * s_n2w[k * HID + j];
        }
        xh_next[n] = make_uint4(packh2(fast_tanh(H[0]), fast_tanh(H[1])),
                                packh2(fast_tanh(H[2]), fast_tanh(H[3])),
                                packh2(fast_tanh(H[4]), fast_tanh(H[5])),
                                packh2(fast_tanh(H[6]), fast_tanh(H[7])));
    }
}

// ---------------------------------------------------------------------------
// Final edge network -> out. Top-half weights in SGPRs, bottom half via LDS
// b128 reads; dots via v_dot2_f32_f16.
// ---------------------------------------------------------------------------
__global__ __launch_bounds__(256) void edge_kernel(const int* __restrict__ row,
                                                   const int* __restrict__ col,
                                                   const uint4* __restrict__ xh,
                                                   const unsigned* __restrict__ xs,
                                                   const float* __restrict__ e1_w,
                                                   const float* __restrict__ e1_b,
                                                   const float* __restrict__ e2_w,
                                                   const float* __restrict__ e2_b,
                                                   float* __restrict__ out) {
    __shared__ unsigned s_top[40];
    __shared__ uint4 s_bot4[10];
    __shared__ float s_scal[17];
    int tid = threadIdx.x;
    unsigned* s_bot = (unsigned*)s_bot4;
    if (tid < 40) {
        int kk = tid >> 3, j = tid & 7;
        s_top[tid] = packh2(e1_w[(2 * kk) * HID + j], e1_w[(2 * kk + 1) * HID + j]);
        s_bot[tid] = packh2(e1_w[(FDIM + 2 * kk) * HID + j], e1_w[(FDIM + 2 * kk + 1) * HID + j]);
    } else if (tid < 48) s_scal[tid - 40] = e1_b[tid - 40];
    else if (tid < 56) s_scal[tid - 40] = e2_w[tid - 48];
    else if (tid == 56) s_scal[16] = e2_b[0];
    __syncthreads();

    unsigned st[40];
#pragma unroll
    for (int i = 0; i < 40; i++) st[i] = rfl_u(s_top[i]);
    float sb[HID], sv[HID];
#pragma unroll
    for (int j = 0; j < HID; j++) { sb[j] = rfl_f(s_scal[j]); sv[j] = rfl_f(s_scal[8 + j]); }
    float sc = rfl_f(s_scal[16]);

    int i = blockIdx.x * 256 + tid;
    if (i >= N_EDGES) return;

    int r = row[i], c = col[i];
    uint4 aq = xh[c]; unsigned ax = xs[c];
    uint4 bq = xh[r]; unsigned bx = xs[r];
    unsigned ap[5] = { aq.x, aq.y, aq.z, aq.w, ax };
    unsigned bp[5] = { bq.x, bq.y, bq.z, bq.w, bx };

    float acc[HID];
#pragma unroll
    for (int j = 0; j < HID; j++) acc[j] = sb[j];
#pragma unroll
    for (int kk = 0; kk < 5; kk++) {
        h2v a = u2h(ap[kk]);
#pragma unroll
        for (int j = 0; j < HID; j++)
            acc[j] = __builtin_amdgcn_fdot2(a, u2h(st[kk * 8 + j]), acc[j], false);
    }
#pragma unroll
    for (int kk = 0; kk < 5; kk++) {
        uint4 wa = s_bot4[2 * kk];
        uint4 wb = s_bot4[2 * kk + 1];
        h2v b = u2h(bp[kk]);
        acc[0] = __builtin_amdgcn_fdot2(b, u2h(wa.x), acc[0], false);
        acc[1] = __builtin_amdgcn_fdot2(b, u2h(wa.y), acc[1], false);
        acc[2] = __builtin_amdgcn_fdot2(b, u2h(wa.z), acc[2], false);
        acc[3] = __builtin_amdgcn_fdot2(b, u2h(wa.w), acc[3], false);
        acc[4] = __builtin_amdgcn_fdot2(b, u2h(wb.x), acc[4], false);
        acc[5] = __builtin_amdgcn_fdot2(b, u2h(wb.y), acc[5], false);
        acc[6] = __builtin_amdgcn_fdot2(b, u2h(wb.z), acc[6], false);
        acc[7] = __builtin_amdgcn_fdot2(b, u2h(wb.w), acc[7], false);
    }

    float d = sc;
#pragma unroll
    for (int j = 0; j < HID; j++) d += fast_tanh(acc[j]) * sv[j];
    out[i] = fast_sigmoid(d);
}

// ---------------------------------------------------------------------------
extern "C" void kernel_launch(void* const* d_in, const int* in_sizes, int n_in,
                              void* d_out, int out_size, void* d_ws, size_t ws_size,
                              hipStream_t stream) {
    const float* x      = (const float*)d_in[0];
    const int*   eidx   = (const int*)d_in[1];
    const float* win_w  = (const float*)d_in[2];
    const float* win_b  = (const float*)d_in[3];
    const float* e1_w   = (const float*)d_in[4];
    const float* e1_b   = (const float*)d_in[5];
    const float* e2_w   = (const float*)d_in[6];
    const float* e2_b   = (const float*)d_in[7];
    const float* n1_w   = (const float*)d_in[8];
    const float* n1_b   = (const float*)d_in[9];
    const float* n2_w   = (const float*)d_in[10];
    const float* n2_b   = (const float*)d_in[11];
    float* out = (float*)d_out;

    const int* row = eidx;
    const int* col = eidx + N_EDGES;

    // Workspace layout (~82 MB):
    char* w = (char*)d_ws;
    uint4* xh0 = (uint4*)w;            w += (size_t)ROWS_PAD * 16;   // 8 MB
    uint4* xh1 = (uint4*)w;            w += (size_t)ROWS_PAD * 16;   // 8 MB
    unsigned* xs = (unsigned*)w;       w += (size_t)ROWS_PAD * 4;    // 2 MB
    unsigned int* binned = (unsigned int*)w; w += (size_t)2 * N_EDGES * 4; // 32 MB
    int* entries = (int*)w;            w += (size_t)2 * N_EDGES * 4; // 32 MB
    int* offs = (int*)w;               w += (size_t)(DSPACE + 64) * 4;
    int* g_cnt = (int*)w;              w += NB * 4;
    int* bucket_base = (int*)w;        w += (NB + 64) * 4;
    int* bucket_cur = (int*)w;

    const int BLK = 256;
    int edge_blocks = (N_EDGES + BLK - 1) / BLK;
    int chunk_blocks = (N_EDGES + 4095) / 4096;

    // --- CSR build ---
    hipMemsetAsync(g_cnt, 0, NB * sizeof(int), stream);
    bucket_hist_kernel<<<chunk_blocks, 256, 0, stream>>>(row, col, g_cnt);
    bucket_scan_kernel<<<1, NB, 0, stream>>>(g_cnt, bucket_base, bucket_cur);
    bin_kernel<<<chunk_blocks, 1024, 0, stream>>>(row, col, bucket_cur, binned);
    csr_kernel<<<NB_USED, 1024, 0, stream>>>(binned, bucket_base, offs, entries);

    // --- input network ---
    input_kernel<<<IN_BLOCKS, BLK, 0, stream>>>(x, win_w, win_b, xh0, xs);

    // --- message-passing iterations (ping-pong H table) ---
    uint4* cur = xh0;
    uint4* nxt = xh1;
    for (int it = 0; it < 3; it++) {
        node_kernel<<<NODE_BLOCKS2, BLK, 0, stream>>>(
            cur, xs, offs, entries, e1_w, e1_b, e2_w, e2_b,
            n1_w, n1_b, n2_w, n2_b, nxt);
        uint4* t = cur; cur = nxt; nxt = t;
    }

    // --- final edge network -> out ---
    edge_kernel<<<edge_blocks, BLK, 0, stream>>>(
        row, col, cur, xs, e1_w, e1_b, e2_w, e2_b, out);
}

// Round 5
// 984.774 us; speedup vs baseline: 1.2012x; 1.0018x over previous
//
#include <hip/hip_runtime.h>
#include <hip/hip_fp16.h>
#include <math.h>

#define N_NODES 500000
#define N_EDGES 4000000
#define FDIM 10   // IN_DIM + HID
#define HID 8

// Dest space: interleaved, dest = 2*col (mi side) or 2*row+1 (mo side).
#define DSPACE (2 * N_NODES)
#define NB 512
#define BSHIFT 11
#define BMASK 2047
#define NB_USED ((DSPACE + BMASK) / 2048)   // 489

#define IN_BLOCKS ((N_NODES + 255) / 256)       // 1954
#define ROWS_PAD (IN_BLOCKS * 256)              // 500224
#define NODE_BLOCKS2 ((N_NODES + 127) / 128)    // 3907 (128 nodes/block, 2 sides)

// packed fp16 pair
typedef _Float16 h2v __attribute__((ext_vector_type(2)));

__device__ __forceinline__ h2v u2h(unsigned x) {
    union { unsigned u; h2v h; } t; t.u = x; return t.h;
}
__device__ __forceinline__ unsigned packh2(float a, float b) {
    union { __half2 h; unsigned u; } t; t.h = __floats2half2_rn(a, b); return t.u;
}
__device__ __forceinline__ float rfl_f(float x) {
    return __int_as_float(__builtin_amdgcn_readfirstlane(__float_as_int(x)));
}
__device__ __forceinline__ unsigned rfl_u(unsigned x) {
    return (unsigned)__builtin_amdgcn_readfirstlane((int)x);
}

// Non-temporal scalar int load for single-use index streams (row/col/offs):
// keeps them from evicting gather-resident node-table lines in L2.
__device__ __forceinline__ int nt_ld_i(const int* p) { return __builtin_nontemporal_load(p); }

// ---------------------------------------------------------------------------
// Fast transcendentals (hw exp2/rcp; error ~1e-6 vs threshold 1.35e-2)
// ---------------------------------------------------------------------------
__device__ __forceinline__ float fast_tanh(float x) {
    float e = __builtin_amdgcn_exp2f(x * 2.885390082f);  // exp(2x)
    return 1.0f - 2.0f * __builtin_amdgcn_rcpf(e + 1.0f);
}
__device__ __forceinline__ float fast_sigmoid(float x) {
    float e = __builtin_amdgcn_exp2f(-1.442695041f * x); // exp(-x)
    return __builtin_amdgcn_rcpf(1.0f + e);
}

// ---------------------------------------------------------------------------
// Input network: H table (fp16, 16 B rows) + static X table (fp16, 4 B rows).
// ---------------------------------------------------------------------------
__global__ __launch_bounds__(256) void input_kernel(const float* __restrict__ x,
                                                    const float* __restrict__ win_w,
                                                    const float* __restrict__ win_b,
                                                    uint4* __restrict__ xh,
                                                    unsigned* __restrict__ xs) {
    int n = blockIdx.x * 256 + threadIdx.x;   // grid covers ROWS_PAD exactly
    float x0 = 0.f, x1 = 0.f;
    if (n < N_NODES) { x0 = x[2 * n]; x1 = x[2 * n + 1]; }
    float h[HID];
#pragma unroll
    for (int j = 0; j < HID; j++)
        h[j] = fast_tanh(x0 * win_w[j] + x1 * win_w[HID + j] + win_b[j]);
    xh[n] = make_uint4(packh2(h[0], h[1]), packh2(h[2], h[3]),
                       packh2(h[4], h[5]), packh2(h[6], h[7]));
    xs[n] = packh2(x0, x1);
}

// ---------------------------------------------------------------------------
// K0: bucket histogram, LDS-staged.
// ---------------------------------------------------------------------------
__global__ void bucket_hist_kernel(const int* __restrict__ row,
                                   const int* __restrict__ col,
                                   int* __restrict__ g_cnt) {
    __shared__ int s_cnt[NB];
    int tid = threadIdx.x;
    for (int i = tid; i < NB; i += 256) s_cnt[i] = 0;
    __syncthreads();
    int base = blockIdx.x * 4096;
#pragma unroll
    for (int k = 0; k < 16; k++) {
        int e = base + k * 256 + tid;
        if (e < N_EDGES) {
            int c = nt_ld_i(col + e), r = nt_ld_i(row + e);
            atomicAdd(&s_cnt[(2 * c) >> BSHIFT], 1);
            atomicAdd(&s_cnt[(2 * r + 1) >> BSHIFT], 1);
        }
    }
    __syncthreads();
    for (int i = tid; i < NB; i += 256) {
        int v = s_cnt[i];
        if (v) atomicAdd(&g_cnt[i], v);
    }
}

// ---------------------------------------------------------------------------
// K1: exclusive scan of bucket counts.
// ---------------------------------------------------------------------------
__global__ void bucket_scan_kernel(const int* __restrict__ g_cnt,
                                   int* __restrict__ bucket_base,
                                   int* __restrict__ bucket_cur) {
    __shared__ int s[NB];
    int t = threadIdx.x;
    int c = g_cnt[t];
    s[t] = c;
    __syncthreads();
    for (int off = 1; off < NB; off <<= 1) {
        int v = (t >= off) ? s[t - off] : 0;
        __syncthreads();
        s[t] += v;
        __syncthreads();
    }
    int ex = s[t] - c;
    bucket_base[t] = ex;
    bucket_cur[t] = ex;
    if (t == NB - 1) bucket_base[NB] = s[t];
}

// ---------------------------------------------------------------------------
// K2: binning into bucket-ordered staging (LDS), coalesced flush.
// ---------------------------------------------------------------------------
__global__ void bin_kernel(const int* __restrict__ row,
                           const int* __restrict__ col,
                           int* __restrict__ bucket_cur,
                           unsigned int* __restrict__ binned) {
    __shared__ int s_cnt[NB];
    __shared__ int s_start[NB];
    __shared__ int s_cur[NB];
    __shared__ int s_gbase[NB];
    __shared__ unsigned int s_items[8192];
    __shared__ unsigned short s_ibkt[8192];

    int tid = threadIdx.x;
    if (tid < NB) s_cnt[tid] = 0;
    __syncthreads();

    int base = blockIdx.x * 4096;
    int cc[4], rr[4];
#pragma unroll
    for (int k = 0; k < 4; k++) {
        int e = base + k * 1024 + tid;
        bool ok = (e < N_EDGES);
        cc[k] = ok ? nt_ld_i(col + e) : -1;
        rr[k] = ok ? nt_ld_i(row + e) : -1;
        if (ok) {
            atomicAdd(&s_cnt[(2 * cc[k]) >> BSHIFT], 1);
            atomicAdd(&s_cnt[(2 * rr[k] + 1) >> BSHIFT], 1);
        }
    }
    __syncthreads();

    if (tid < NB) s_start[tid] = s_cnt[tid];
    __syncthreads();
    for (int off = 1; off < NB; off <<= 1) {
        int v = 0;
        if (tid < NB && tid >= off) v = s_start[tid - off];
        __syncthreads();
        if (tid < NB) s_start[tid] += v;
        __syncthreads();
    }
    if (tid < NB) {
        int ex = s_start[tid] - s_cnt[tid];
        s_start[tid] = ex;
        s_cur[tid] = ex;
    }
    __syncthreads();

#pragma unroll
    for (int k = 0; k < 4; k++) {
        if (cc[k] >= 0) {
            int d0 = 2 * cc[k];
            int b0 = d0 >> BSHIFT;
            int s0 = atomicAdd(&s_cur[b0], 1);
            s_items[s0] = ((unsigned)(d0 & BMASK) << 19) | (unsigned)rr[k];
            s_ibkt[s0] = (unsigned short)b0;
            int d1 = 2 * rr[k] + 1;
            int b1 = d1 >> BSHIFT;
            int s1 = atomicAdd(&s_cur[b1], 1);
            s_items[s1] = ((unsigned)(d1 & BMASK) << 19) | (unsigned)cc[k];
            s_ibkt[s1] = (unsigned short)b1;
        }
    }
    __syncthreads();

    if (tid < NB) s_gbase[tid] = atomicAdd(&bucket_cur[tid], s_cnt[tid]);
    __syncthreads();

    int tot = s_start[NB - 1] + s_cnt[NB - 1];
    for (int s = tid; s < tot; s += 1024) {
        int b = s_ibkt[s];
        int g = s_gbase[b] + (s - s_start[b]);
        binned[g] = s_items[s];
    }
}

// ---------------------------------------------------------------------------
// K3: CSR finalize per bucket, all fine-grained work in LDS.
// ---------------------------------------------------------------------------
__global__ void csr_kernel(const unsigned int* __restrict__ binned,
                           const int* __restrict__ bucket_base,
                           int* __restrict__ offs,
                           int* __restrict__ entries) {
    __shared__ int s_deg[2048];
    __shared__ int s_cur[2048];
    __shared__ int s_pair[1024];

    int t = threadIdx.x;
    int b = blockIdx.x;
    if (b == 0 && t == 0) offs[DSPACE] = 2 * N_EDGES;

    int ebase = bucket_base[b];
    int eend = bucket_base[b + 1];

    s_deg[t] = 0;
    s_deg[t + 1024] = 0;
    __syncthreads();

    for (int p = ebase + t; p < eend; p += 1024)
        atomicAdd(&s_deg[binned[p] >> 19], 1);
    __syncthreads();

    int d0 = s_deg[2 * t], d1 = s_deg[2 * t + 1];
    s_pair[t] = d0 + d1;
    __syncthreads();
    for (int off = 1; off < 1024; off <<= 1) {
        int v = (t >= off) ? s_pair[t - off] : 0;
        __syncthreads();
        s_pair[t] += v;
        __syncthreads();
    }
    int pex = s_pair[t] - (d0 + d1);
    s_cur[2 * t] = pex;
    s_cur[2 * t + 1] = pex + d0;

    int dest0 = b * 2048 + 2 * t;
    if (dest0 < DSPACE) offs[dest0] = ebase + pex;
    if (dest0 + 1 < DSPACE) offs[dest0 + 1] = ebase + pex + d0;
    __syncthreads();

    for (int p = ebase + t; p < eend; p += 1024) {
        unsigned int it = binned[p];
        int dl = it >> 19;
        int other = it & 0x7FFFF;
        int pos = atomicAdd(&s_cur[dl], 1);
        entries[ebase + pos] = other;
    }
}

// ---------------------------------------------------------------------------
// Fused gather + edge-MLP + node network.
//   256 threads / 128 nodes per block: tid<128 -> dest 2n (mi side),
//   tid>=128 -> dest 2n+1 (mo side). Side is WAVE-uniform, other-half e1
//   weights in SGPRs, dots via v_dot2_f32_f16 on fp16-packed rows.
//   Depth-3 software pipeline: index prefetched 3 ahead, row loaded 2 ahead,
//   so ~2 independent row-misses are in flight per lane.
// ---------------------------------------------------------------------------
__global__ __launch_bounds__(256, 6) void node_kernel(
        const uint4* __restrict__ xh,
        const unsigned* __restrict__ xs,
        const int* __restrict__ offs,
        const int* __restrict__ entries,
        const float* __restrict__ e1_w,
        const float* __restrict__ e1_b,
        const float* __restrict__ e2_w,
        const float* __restrict__ e2_b,
        const float* __restrict__ n1_w,
        const float* __restrict__ n1_b,
        const float* __restrict__ n2_w,
        const float* __restrict__ n2_b,
        uint4* __restrict__ xh_next) {
    __shared__ uint4 s_wtop4[10];     // e1_w rows 0..9  (col half), packed half2
    __shared__ uint4 s_wbot4[10];     // e1_w rows 10..19 (row half), packed half2
    __shared__ float s_scal[17];      // e1b[8], e2w[8], e2b
    __shared__ float s_n1w[30 * HID];
    __shared__ float s_n1b[HID];
    __shared__ float s_n2w[HID * HID];
    __shared__ float s_n2b[HID];
    __shared__ float s_mo[128 * 11];  // stride 11 (coprime 32 -> no conflicts)

    int tid = threadIdx.x;
    if (tid < 40) {
        int kk = tid >> 3, j = tid & 7;
        ((unsigned*)s_wtop4)[tid] = packh2(e1_w[(2 * kk) * HID + j],
                                           e1_w[(2 * kk + 1) * HID + j]);
        ((unsigned*)s_wbot4)[tid] = packh2(e1_w[(FDIM + 2 * kk) * HID + j],
                                           e1_w[(FDIM + 2 * kk + 1) * HID + j]);
    } else if (tid < 48) s_scal[tid - 40] = e1_b[tid - 40];
    else if (tid < 56) s_scal[tid - 40] = e2_w[tid - 48];
    else if (tid == 56) s_scal[16] = e2_b[0];
    if (tid < 240) s_n1w[tid] = n1_w[tid];
    else if (tid < 248) s_n1b[tid - 240] = n1_b[tid - 240];
    if (tid < 64) s_n2w[tid] = n2_w[tid];
    else if (tid < 72) s_n2b[tid - 64] = n2_b[tid - 64];
    __syncthreads();

    bool up = tid >= 128;             // wave-uniform
    int lt = up ? tid - 128 : tid;
    int n = blockIdx.x * 128 + lt;
    bool act = n < N_NODES;

    // mi (dest 2n): self = top half, other = bottom half. mo: swapped.
    const uint4* selfw4 = up ? s_wbot4 : s_wtop4;
    const unsigned* othw = up ? (const unsigned*)s_wtop4 : (const unsigned*)s_wbot4;

    // wave-uniform constants -> SGPRs
    unsigned so[40];
#pragma unroll
    for (int i = 0; i < 40; i++) so[i] = rfl_u(othw[i]);
    float sb[HID], sv[HID];
#pragma unroll
    for (int j = 0; j < HID; j++) { sb[j] = rfl_f(s_scal[j]); sv[j] = rfl_f(s_scal[8 + j]); }
    float sc = rfl_f(s_scal[16]);

    unsigned xp[5] = {0, 0, 0, 0, 0};
    float m[FDIM];
#pragma unroll
    for (int k = 0; k < FDIM; k++) m[k] = 0.f;

    if (act) {
        uint4 xq = xh[n]; unsigned xx = xs[n];
        xp[0] = xq.x; xp[1] = xq.y; xp[2] = xq.z; xp[3] = xq.w; xp[4] = xx;

        // self-half dot (bias folded), inputs stay fp16-packed
        float us[HID];
#pragma unroll
        for (int j = 0; j < HID; j++) us[j] = sb[j];
#pragma unroll
        for (int kk = 0; kk < 5; kk++) {
            uint4 wa = selfw4[2 * kk];
            uint4 wb = selfw4[2 * kk + 1];
            h2v a = u2h(xp[kk]);
            us[0] = __builtin_amdgcn_fdot2(a, u2h(wa.x), us[0], false);
            us[1] = __builtin_amdgcn_fdot2(a, u2h(wa.y), us[1], false);
            us[2] = __builtin_amdgcn_fdot2(a, u2h(wa.z), us[2], false);
            us[3] = __builtin_amdgcn_fdot2(a, u2h(wa.w), us[3], false);
            us[4] = __builtin_amdgcn_fdot2(a, u2h(wb.x), us[4], false);
            us[5] = __builtin_amdgcn_fdot2(a, u2h(wb.y), us[5], false);
            us[6] = __builtin_amdgcn_fdot2(a, u2h(wb.z), us[6], false);
            us[7] = __builtin_amdgcn_fdot2(a, u2h(wb.w), us[7], false);
        }

        int dest = 2 * n + (up ? 1 : 0);
        int p0 = nt_ld_i(offs + dest), p1 = nt_ld_i(offs + dest + 1);
        int np = p1 - p0;

        if (np > 0) {
            // pipeline preamble: rows for p0, p0+1; index for p0+2
            int o0 = entries[p0];
            uint4 A = xh[o0]; unsigned Ax = xs[o0];
            int i1 = (np > 1) ? p0 + 1 : p0;
            int o1 = entries[i1];
            uint4 B = xh[o1]; unsigned Bx = xs[o1];
            int i2 = (np > 2) ? p0 + 2 : i1;
            int o2 = entries[i2];

            for (int p = p0; p < p1; ++p) {
                // prefetch: index 3 ahead, row 2 ahead (o2 ready from last iter)
                int i3 = (p + 3 < p1) ? p + 3 : p1 - 1;
                int o3 = entries[i3];
                uint4 C = xh[o2]; unsigned Cx = xs[o2];

                unsigned cp[5] = { A.x, A.y, A.z, A.w, Ax };
                float acc[HID];
#pragma unroll
                for (int j = 0; j < HID; j++) acc[j] = us[j];
#pragma unroll
                for (int kk = 0; kk < 5; kk++) {
                    h2v a = u2h(cp[kk]);
#pragma unroll
                    for (int j = 0; j < HID; j++)
                        acc[j] = __builtin_amdgcn_fdot2(a, u2h(so[kk * 8 + j]), acc[j], false);
                }
                float d = sc;
#pragma unroll
                for (int j = 0; j < HID; j++) d += fast_tanh(acc[j]) * sv[j];
                float e = fast_sigmoid(d);
#pragma unroll
                for (int kk = 0; kk < 5; kk++) {
                    h2v a = u2h(cp[kk]);
                    m[2 * kk]     += e * (float)a.x;
                    m[2 * kk + 1] += e * (float)a.y;
                }
                A = B; Ax = Bx; B = C; Bx = Cx; o2 = o3;
            }
        }
    }

    if (up && act) {
        int lb = lt * 11;
#pragma unroll
        for (int k = 0; k < FDIM; k++) s_mo[lb + k] = m[k];
    }
    __syncthreads();

    if (!up && act) {
        int lb = lt * 11;
        float xn[FDIM];
#pragma unroll
        for (int kk = 0; kk < 5; kk++) {
            h2v a = u2h(xp[kk]);
            xn[2 * kk] = (float)a.x; xn[2 * kk + 1] = (float)a.y;
        }
        float h1[HID];
#pragma unroll
        for (int j = 0; j < HID; j++) h1[j] = s_n1b[j];
#pragma unroll
        for (int k = 0; k < FDIM; k++) {
            float mo_k = s_mo[lb + k];
#pragma unroll
            for (int j = 0; j < HID; j++) {
                h1[j] += m[k]  * s_n1w[k * HID + j];
                h1[j] += mo_k  * s_n1w[(FDIM + k) * HID + j];
                h1[j] += xn[k] * s_n1w[(2 * FDIM + k) * HID + j];
            }
        }
#pragma unroll
        for (int j = 0; j < HID; j++) h1[j] = fast_tanh(h1[j]);

        float H[HID];
#pragma unroll
        for (int j = 0; j < HID; j++) H[j] = s_n2b[j];
#pragma unroll
        for (int k = 0; k < HID; k++) {
#pragma unroll
            for (int j = 0; j < HID; j++) H[j] += h1[k] * s_n2w[k * HID + j];
        }
        xh_next[n] = make_uint4(packh2(fast_tanh(H[0]), fast_tanh(H[1])),
                                packh2(fast_tanh(H[2]), fast_tanh(H[3])),
                                packh2(fast_tanh(H[4]), fast_tanh(H[5])),
                                packh2(fast_tanh(H[6]), fast_tanh(H[7])));
    }
}

// ---------------------------------------------------------------------------
// Final edge network -> out. Top-half weights in SGPRs, bottom half via LDS
// b128 reads; dots via v_dot2_f32_f16. Index streams non-temporal.
// ---------------------------------------------------------------------------
__global__ __launch_bounds__(256) void edge_kernel(const int* __restrict__ row,
                                                   const int* __restrict__ col,
                                                   const uint4* __restrict__ xh,
                                                   const unsigned* __restrict__ xs,
                                                   const float* __restrict__ e1_w,
                                                   const float* __restrict__ e1_b,
                                                   const float* __restrict__ e2_w,
                                                   const float* __restrict__ e2_b,
                                                   float* __restrict__ out) {
    __shared__ unsigned s_top[40];
    __shared__ uint4 s_bot4[10];
    __shared__ float s_scal[17];
    int tid = threadIdx.x;
    unsigned* s_bot = (unsigned*)s_bot4;
    if (tid < 40) {
        int kk = tid >> 3, j = tid & 7;
        s_top[tid] = packh2(e1_w[(2 * kk) * HID + j], e1_w[(2 * kk + 1) * HID + j]);
        s_bot[tid] = packh2(e1_w[(FDIM + 2 * kk) * HID + j], e1_w[(FDIM + 2 * kk + 1) * HID + j]);
    } else if (tid < 48) s_scal[tid - 40] = e1_b[tid - 40];
    else if (tid < 56) s_scal[tid - 40] = e2_w[tid - 48];
    else if (tid == 56) s_scal[16] = e2_b[0];
    __syncthreads();

    unsigned st[40];
#pragma unroll
    for (int i = 0; i < 40; i++) st[i] = rfl_u(s_top[i]);
    float sb[HID], sv[HID];
#pragma unroll
    for (int j = 0; j < HID; j++) { sb[j] = rfl_f(s_scal[j]); sv[j] = rfl_f(s_scal[8 + j]); }
    float sc = rfl_f(s_scal[16]);

    int i = blockIdx.x * 256 + tid;
    if (i >= N_EDGES) return;

    int r = nt_ld_i(row + i), c = nt_ld_i(col + i);
    uint4 aq = xh[c]; unsigned ax = xs[c];
    uint4 bq = xh[r]; unsigned bx = xs[r];
    unsigned ap[5] = { aq.x, aq.y, aq.z, aq.w, ax };
    unsigned bp[5] = { bq.x, bq.y, bq.z, bq.w, bx };

    float acc[HID];
#pragma unroll
    for (int j = 0; j < HID; j++) acc[j] = sb[j];
#pragma unroll
    for (int kk = 0; kk < 5; kk++) {
        h2v a = u2h(ap[kk]);
#pragma unroll
        for (int j = 0; j < HID; j++)
            acc[j] = __builtin_amdgcn_fdot2(a, u2h(st[kk * 8 + j]), acc[j], false);
    }
#pragma unroll
    for (int kk = 0; kk < 5; kk++) {
        uint4 wa = s_bot4[2 * kk];
        uint4 wb = s_bot4[2 * kk + 1];
        h2v b = u2h(bp[kk]);
        acc[0] = __builtin_amdgcn_fdot2(b, u2h(wa.x), acc[0], false);
        acc[1] = __builtin_amdgcn_fdot2(b, u2h(wa.y), acc[1], false);
        acc[2] = __builtin_amdgcn_fdot2(b, u2h(wa.z), acc[2], false);
        acc[3] = __builtin_amdgcn_fdot2(b, u2h(wa.w), acc[3], false);
        acc[4] = __builtin_amdgcn_fdot2(b, u2h(wb.x), acc[4], false);
        acc[5] = __builtin_amdgcn_fdot2(b, u2h(wb.y), acc[5], false);
        acc[6] = __builtin_amdgcn_fdot2(b, u2h(wb.z), acc[6], false);
        acc[7] = __builtin_amdgcn_fdot2(b, u2h(wb.w), acc[7], false);
    }

    float d = sc;
#pragma unroll
    for (int j = 0; j < HID; j++) d += fast_tanh(acc[j]) * sv[j];
    out[i] = fast_sigmoid(d);
}

// ---------------------------------------------------------------------------
extern "C" void kernel_launch(void* const* d_in, const int* in_sizes, int n_in,
                              void* d_out, int out_size, void* d_ws, size_t ws_size,
                              hipStream_t stream) {
    const float* x      = (const float*)d_in[0];
    const int*   eidx   = (const int*)d_in[1];
    const float* win_w  = (const float*)d_in[2];
    const float* win_b  = (const float*)d_in[3];
    const float* e1_w   = (const float*)d_in[4];
    const float* e1_b   = (const float*)d_in[5];
    const float* e2_w   = (const float*)d_in[6];
    const float* e2_b   = (const float*)d_in[7];
    const float* n1_w   = (const float*)d_in[8];
    const float* n1_b   = (const float*)d_in[9];
    const float* n2_w   = (const float*)d_in[10];
    const float* n2_b   = (const float*)d_in[11];
    float* out = (float*)d_out;

    const int* row = eidx;
    const int* col = eidx + N_EDGES;

    // Workspace layout (~90 MB):
    char* w = (char*)d_ws;
    uint4* xh0 = (uint4*)w;            w += (size_t)ROWS_PAD * 16;   // 8 MB
    uint4* xh1 = (uint4*)w;            w += (size_t)ROWS_PAD * 16;   // 8 MB
    unsigned* xs = (unsigned*)w;       w += (size_t)ROWS_PAD * 4;    // 2 MB
    unsigned int* binned = (unsigned int*)w; w += (size_t)2 * N_EDGES * 4; // 32 MB
    int* entries = (int*)w;            w += (size_t)2 * N_EDGES * 4; // 32 MB
    int* offs = (int*)w;               w += (size_t)(DSPACE + 64) * 4;
    int* g_cnt = (int*)w;              w += NB * 4;
    int* bucket_base = (int*)w;        w += (NB + 64) * 4;
    int* bucket_cur = (int*)w;

    const int BLK = 256;
    int edge_blocks = (N_EDGES + BLK - 1) / BLK;
    int chunk_blocks = (N_EDGES + 4095) / 4096;

    // --- CSR build ---
    hipMemsetAsync(g_cnt, 0, NB * sizeof(int), stream);
    bucket_hist_kernel<<<chunk_blocks, 256, 0, stream>>>(row, col, g_cnt);
    bucket_scan_kernel<<<1, NB, 0, stream>>>(g_cnt, bucket_base, bucket_cur);
    bin_kernel<<<chunk_blocks, 1024, 0, stream>>>(row, col, bucket_cur, binned);
    csr_kernel<<<NB_USED, 1024, 0, stream>>>(binned, bucket_base, offs, entries);

    // --- input network ---
    input_kernel<<<IN_BLOCKS, BLK, 0, stream>>>(x, win_w, win_b, xh0, xs);

    // --- message-passing iterations (ping-pong H table) ---
    uint4* cur = xh0;
    uint4* nxt = xh1;
    for (int it = 0; it < 3; it++) {
        node_kernel<<<NODE_BLOCKS2, BLK, 0, stream>>>(
            cur, xs, offs, entries, e1_w, e1_b, e2_w, e2_b,
            n1_w, n1_b, n2_w, n2_b, nxt);
        uint4* t = cur; cur = nxt; nxt = t;
    }

    // --- final edge network -> out ---
    edge_kernel<<<edge_blocks, BLK, 0, stream>>>(
        row, col, cur, xs, e1_w, e1_b, e2_w, e2_b, out);
}